// Round 15
// baseline (169.490 us; speedup 1.0000x reference)
//
#include <hip/hip_runtime.h>

// VQ-VAE VectorQuantizer2 forward for MI355X (gfx950)
// z:   (8, 8, 32, 32, 32) fp32  [b, c, l, h, w], c = e_dim = 8
// emb: (1024, 8) fp32
// out: [ z_q (2097152) | loss (1) | unique (1) | idx (262144) ]  all as fp32
//
// History: R8 P=1 s_load 125us | R10 P=4 s_load 180us (dependent-s_load
// serialization) | R11 P=4 LDS 102us VALUBusy 62% | R12 +SW-pipeline
// NEUTRAL 103us -> stall is LDS *throughput* (4 waves/CU share one LDS
// pipe; broadcast ds_read return ~240cyc/code-iter/CU), not latency.
// R13: hybrid sourcing — even 4-code groups via LDS, odd groups via
// uniform global (scalar s_load, constant cache) -> LDS traffic halves,
// VALU (104cyc/code-iter) becomes bottleneck. STEP arithmetic UNCHANGED
// (bit-exact idx validated R8/R10/R11/R12).
//
// ws layout (bytes):
//   [0,    4096)  used[1024]  int    (zeroed by vq_prep each launch)
//   [4096, 8192)  e2g[1024]   float  (||e_i||^2, by vq_prep)
//   [8192, 9216)  partials[256] float (per-block loss sums)

#define NE 1024
#define ED 8
#define NPOS 262144        // 8 * 32*32*32
#define SPAT 32768         // 32*32*32
#define CH_STRIDE 32768    // channel stride in floats
#define BATCH_STRIDE 262144// batch stride in floats (8 channels * 32768)
#define LOSS_OFF 2097152
#define UNIQ_OFF 2097153
#define IDX_OFF 2097154
#define PPT 4              // positions per thread
#define TQ 65536           // NPOS / PPT (position stride between the P slots)

__global__ __launch_bounds__(256)
void vq_prep(const float* __restrict__ emb, int* __restrict__ used,
             float* __restrict__ e2g) {
    int j = blockIdx.x * 256 + threadIdx.x;
    if (j < NE) {
        used[j] = 0;
        const float* e = emb + j * ED;
        float s;
        {
            // mul-then-add, no contraction (mirror elementwise-square+reduce)
            #pragma clang fp contract(off)
            float acc = e[0] * e[0];
            #pragma unroll
            for (int k = 1; k < ED; ++k) acc += e[k] * e[k];
            s = acc;
        }
        e2g[j] = s;
    }
}

__global__ __launch_bounds__(256)
void vq_main(const float* __restrict__ z, const float* __restrict__ emb,
             const float* __restrict__ e2g, float* __restrict__ out,
             int* __restrict__ used, float* __restrict__ partials) {
    const int tid = threadIdx.x;
    const int t0 = blockIdx.x * 256 + tid;   // 0..65535

    // --- Stage codebook (32 KB) + norms (4 KB) into LDS -----------------
    // (Only even 4-code groups are read back from LDS; odd groups come
    //  from global via scalar s_load. Stage all of it: simpler indexing.)
    __shared__ float4 cbl[NE * 2];   // [2i]=code i floats 0..3, [2i+1]=4..7
    __shared__ float  e2l[NE];
    const float4* cbg = (const float4*)emb;
    {
        #pragma unroll
        for (int k = 0; k < 8; ++k) cbl[tid + k * 256] = cbg[tid + k * 256];
        #pragma unroll
        for (int k = 0; k < 4; ++k) e2l[tid + k * 256] = e2g[tid + k * 256];
    }

    // --- Load PPT positions' vectors (overlaps with staging) ------------
    float zv[PPT][ED];
    float z2[PPT];
    #pragma unroll
    for (int p = 0; p < PPT; ++p) {
        const int n = t0 + p * TQ;
        const int b = n >> 15;              // n / SPAT
        const int s = n & (SPAT - 1);
        const float* zp = z + b * BATCH_STRIDE + s;
        #pragma unroll
        for (int c = 0; c < ED; ++c) zv[p][c] = zp[c * CH_STRIDE];
        {
            #pragma clang fp contract(off)
            float acc = zv[p][0] * zv[p][0];
            #pragma unroll
            for (int c = 1; c < ED; ++c) acc += zv[p][c] * zv[p][c];
            z2[p] = acc;
        }
    }
    __syncthreads();

    float best0 = 3.4e38f, best1 = 3.4e38f, best2 = 3.4e38f, best3 = 3.4e38f;
    int bi0 = 0, bi1 = 0, bi2 = 0, bi3 = 0;

    // EXACT same per-position arithmetic as the R8-validated kernel:
    // sequential ascending-k FMA dot, d = fmaf(-2,dot,z2+e2), strict <.
    #define STEP(pp, bestv, biv)                                  \
        {                                                         \
            float dot = zv[pp][0] * ea.x;                         \
            dot = fmaf(zv[pp][1], ea.y, dot);                     \
            dot = fmaf(zv[pp][2], ea.z, dot);                     \
            dot = fmaf(zv[pp][3], ea.w, dot);                     \
            dot = fmaf(zv[pp][4], eb.x, dot);                     \
            dot = fmaf(zv[pp][5], eb.y, dot);                     \
            dot = fmaf(zv[pp][6], eb.z, dot);                     \
            dot = fmaf(zv[pp][7], eb.w, dot);                     \
            const float d = fmaf(-2.0f, dot, z2[pp] + e2);        \
            if (d < bestv) { bestv = d; biv = i; }                \
        }

    // Group-of-4 load from LDS (VGPR ds_read path).
    #define LOADG_L(base, EA, EB, E2)                             \
        _Pragma("unroll")                                         \
        for (int k = 0; k < 4; ++k) {                             \
            EA[k] = cbl[2 * ((base) + k)];                        \
            EB[k] = cbl[2 * ((base) + k) + 1];                    \
            E2[k] = e2l[(base) + k];                              \
        }

    // Group-of-4 load from global, wave-uniform address -> scalar s_load
    // (constant cache; no LDS-pipe or VALU cost).
    #define LOADG_G(base, EA, EB, E2)                             \
        _Pragma("unroll")                                         \
        for (int k = 0; k < 4; ++k) {                             \
            EA[k] = cbg[2 * ((base) + k)];                        \
            EB[k] = cbg[2 * ((base) + k) + 1];                    \
            E2[k] = e2g[(base) + k];                              \
        }

    // Compute 4 codes x 4 positions from a register buffer.
    #define STEP4(EA, EB, E2, base)                               \
        _Pragma("unroll")                                         \
        for (int k = 0; k < 4; ++k) {                             \
            const float4 ea = EA[k];                              \
            const float4 eb = EB[k];                              \
            const float e2 = E2[k];                               \
            const int i = (base) + k;                             \
            STEP(0, best0, bi0)                                   \
            STEP(1, best1, bi1)                                   \
            STEP(2, best2, bi2)                                   \
            STEP(3, best3, bi3)                                   \
        }

    // Hybrid pipeline: A groups from LDS, B groups from scalar path.
    // Each ~208-cyc STEP4 covers the other source's fetch latency; LDS
    // pipe sees half the traffic (60cyc/code/CU < VALU 104cyc/code/SIMD).
    float4 Aea[4], Aeb[4]; float Ae2[4];
    float4 Bea[4], Beb[4]; float Be2[4];
    LOADG_L(0, Aea, Aeb, Ae2)
    for (int i0 = 0; i0 < NE - 8; i0 += 8) {
        LOADG_G(i0 + 4, Bea, Beb, Be2)
        STEP4(Aea, Aeb, Ae2, i0)
        LOADG_L(i0 + 8, Aea, Aeb, Ae2)
        STEP4(Bea, Beb, Be2, i0 + 4)
    }
    // Tail: i0 = NE-8; A holds group for NE-8.
    LOADG_G(NE - 4, Bea, Beb, Be2)
    STEP4(Aea, Aeb, Ae2, NE - 8)
    STEP4(Bea, Beb, Be2, NE - 4)

    #undef STEP4
    #undef LOADG_L
    #undef LOADG_G
    #undef STEP

    // Epilogue per position: gather code (global, L1/L2-hot; unchanged
    // validated path), write z_q + idx, loss partial.
    float lacc = 0.0f;
    #define EPI(pp, biv)                                          \
        {                                                         \
            const int n = t0 + pp * TQ;                           \
            const int b = n >> 15;                                \
            const int s = n & (SPAT - 1);                         \
            const float4 wa = cbg[2 * biv];                       \
            const float4 wb = cbg[2 * biv + 1];                   \
            float ev[ED] = {wa.x, wa.y, wa.z, wa.w,               \
                            wb.x, wb.y, wb.z, wb.w};              \
            float* outq = out + b * BATCH_STRIDE + s;             \
            _Pragma("unroll")                                     \
            for (int c = 0; c < ED; ++c) {                        \
                const float diff = ev[c] - zv[pp][c];             \
                lacc = fmaf(diff, diff, lacc);                    \
                outq[c * CH_STRIDE] = ev[c];                      \
            }                                                     \
            out[IDX_OFF + n] = (float)biv;                        \
            used[biv] = 1;                                        \
        }

    EPI(0, bi0)
    EPI(1, bi1)
    EPI(2, bi2)
    EPI(3, bi3)
    #undef EPI

    // Deterministic block-tree reduction of loss partial (graph replay must
    // revalidate bit-identically -> no float atomics)
    __shared__ float red[256];
    red[tid] = lacc;
    __syncthreads();
    #pragma unroll
    for (int off = 128; off > 0; off >>= 1) {
        if (tid < off) red[tid] += red[tid + off];
        __syncthreads();
    }
    if (tid == 0) partials[blockIdx.x] = red[0];
}

__global__ __launch_bounds__(256)
void vq_final(const float* __restrict__ partials, const int* __restrict__ used,
              float* __restrict__ out) {
    __shared__ float sred[256];
    __shared__ int ured[256];
    const int t = threadIdx.x;
    sred[t] = partials[t];
    ured[t] = (used[t] ? 1 : 0) + (used[t + 256] ? 1 : 0)
            + (used[t + 512] ? 1 : 0) + (used[t + 768] ? 1 : 0);
    __syncthreads();
    for (int off = 128; off > 0; off >>= 1) {
        if (t < off) { sred[t] += sred[t + off]; ured[t] += ured[t + off]; }
        __syncthreads();
    }
    if (t == 0) {
        const float M = sred[0] * (1.0f / 2097152.0f);  // exact pow2 scale
        out[LOSS_OFF] = 0.25f * M + M;   // beta*mean + mean (forward values equal)
        out[UNIQ_OFF] = (float)ured[0];
    }
}

extern "C" void kernel_launch(void* const* d_in, const int* in_sizes, int n_in,
                              void* d_out, int out_size, void* d_ws, size_t ws_size,
                              hipStream_t stream) {
    const float* z   = (const float*)d_in[0];
    const float* emb = (const float*)d_in[1];
    float* out = (float*)d_out;

    int*   used     = (int*)d_ws;
    float* e2g      = (float*)((char*)d_ws + 4096);
    float* partials = (float*)((char*)d_ws + 8192);

    vq_prep<<<4, 256, 0, stream>>>(emb, used, e2g);
    vq_main<<<NPOS / (256 * PPT), 256, 0, stream>>>(z, emb, e2g, out, used, partials);
    vq_final<<<1, 256, 0, stream>>>(partials, used, out);
}

// Round 16
// 146.570 us; speedup vs baseline: 1.1564x; 1.1564x over previous
//
#include <hip/hip_runtime.h>

// VQ-VAE VectorQuantizer2 forward for MI355X (gfx950)
// z:   (8, 8, 32, 32, 32) fp32  [b, c, l, h, w], c = e_dim = 8
// emb: (1024, 8) fp32
// out: [ z_q (2097152) | loss (1) | unique (1) | idx (262144) ]  all as fp32
//
// History: R8 P=1 s_load 125us | R10 P=4 s_load 180us | R11 P=4 LDS 102us
// VALUBusy 62% | R12 +SW-pipe NEUTRAL 103us | R15 hybrid s_load/LDS 121us
// REGRESSION (scalar path misses K$ -> L2-latency stalls; LDS-throughput
// theory REFUTED twice). Standing: ~240cyc/code-iter = ~150 VALU-issue +
// ~90 stall, uncoverable at 1 wave/SIMD (grid-limited).
// R16: PPT=2 -> 512 blocks = 2 waves/SIMD; second wave covers the stall
// (m114 co-scheduling). All-LDS A/B prefetch structure kept from R12.
// STEP arithmetic UNCHANGED (bit-exact idx validated R8/R10/R11/R12/R15).
//
// ws layout (bytes):
//   [0,    4096)  used[1024]  int    (zeroed by vq_prep each launch)
//   [4096, 8192)  e2g[1024]   float  (||e_i||^2, by vq_prep)
//   [8192, 10240) partials[512] float (per-block loss sums)

#define NE 1024
#define ED 8
#define NPOS 262144        // 8 * 32*32*32
#define SPAT 32768         // 32*32*32
#define CH_STRIDE 32768    // channel stride in floats
#define BATCH_STRIDE 262144// batch stride in floats (8 channels * 32768)
#define LOSS_OFF 2097152
#define UNIQ_OFF 2097153
#define IDX_OFF 2097154
#define PPT 2              // positions per thread
#define TQ 131072          // NPOS / PPT (position stride between the P slots)
#define NBLK 512           // NPOS / (256*PPT)

__global__ __launch_bounds__(256)
void vq_prep(const float* __restrict__ emb, int* __restrict__ used,
             float* __restrict__ e2g) {
    int j = blockIdx.x * 256 + threadIdx.x;
    if (j < NE) {
        used[j] = 0;
        const float* e = emb + j * ED;
        float s;
        {
            // mul-then-add, no contraction (mirror elementwise-square+reduce)
            #pragma clang fp contract(off)
            float acc = e[0] * e[0];
            #pragma unroll
            for (int k = 1; k < ED; ++k) acc += e[k] * e[k];
            s = acc;
        }
        e2g[j] = s;
    }
}

__global__ __launch_bounds__(256)
void vq_main(const float* __restrict__ z, const float* __restrict__ emb,
             const float* __restrict__ e2g, float* __restrict__ out,
             int* __restrict__ used, float* __restrict__ partials) {
    const int tid = threadIdx.x;
    const int t0 = blockIdx.x * 256 + tid;   // 0..131071

    // --- Stage codebook (32 KB) + norms (4 KB) into LDS -----------------
    __shared__ float4 cbl[NE * 2];   // [2i]=code i floats 0..3, [2i+1]=4..7
    __shared__ float  e2l[NE];
    const float4* cbg = (const float4*)emb;
    {
        #pragma unroll
        for (int k = 0; k < 8; ++k) cbl[tid + k * 256] = cbg[tid + k * 256];
        #pragma unroll
        for (int k = 0; k < 4; ++k) e2l[tid + k * 256] = e2g[tid + k * 256];
    }

    // --- Load PPT positions' vectors (overlaps with staging) ------------
    float zv[PPT][ED];
    float z2[PPT];
    #pragma unroll
    for (int p = 0; p < PPT; ++p) {
        const int n = t0 + p * TQ;
        const int b = n >> 15;              // n / SPAT
        const int s = n & (SPAT - 1);
        const float* zp = z + b * BATCH_STRIDE + s;
        #pragma unroll
        for (int c = 0; c < ED; ++c) zv[p][c] = zp[c * CH_STRIDE];
        {
            #pragma clang fp contract(off)
            float acc = zv[p][0] * zv[p][0];
            #pragma unroll
            for (int c = 1; c < ED; ++c) acc += zv[p][c] * zv[p][c];
            z2[p] = acc;
        }
    }
    __syncthreads();

    float best0 = 3.4e38f, best1 = 3.4e38f;
    int bi0 = 0, bi1 = 0;

    // EXACT same per-position arithmetic as the R8-validated kernel:
    // sequential ascending-k FMA dot, d = fmaf(-2,dot,z2+e2), strict <.
    #define STEP(pp, bestv, biv)                                  \
        {                                                         \
            float dot = zv[pp][0] * ea.x;                         \
            dot = fmaf(zv[pp][1], ea.y, dot);                     \
            dot = fmaf(zv[pp][2], ea.z, dot);                     \
            dot = fmaf(zv[pp][3], ea.w, dot);                     \
            dot = fmaf(zv[pp][4], eb.x, dot);                     \
            dot = fmaf(zv[pp][5], eb.y, dot);                     \
            dot = fmaf(zv[pp][6], eb.z, dot);                     \
            dot = fmaf(zv[pp][7], eb.w, dot);                     \
            const float d = fmaf(-2.0f, dot, z2[pp] + e2);        \
            if (d < bestv) { bestv = d; biv = i; }                \
        }

    // Group-of-4 load from LDS (uniform address -> broadcast, conflict-free)
    #define LOADG_L(base, EA, EB, E2)                             \
        _Pragma("unroll")                                         \
        for (int k = 0; k < 4; ++k) {                             \
            EA[k] = cbl[2 * ((base) + k)];                        \
            EB[k] = cbl[2 * ((base) + k) + 1];                    \
            E2[k] = e2l[(base) + k];                              \
        }

    // Compute 4 codes x 2 positions from a register buffer.
    #define STEP4(EA, EB, E2, base)                               \
        _Pragma("unroll")                                         \
        for (int k = 0; k < 4; ++k) {                             \
            const float4 ea = EA[k];                              \
            const float4 eb = EB[k];                              \
            const float e2 = E2[k];                               \
            const int i = (base) + k;                             \
            STEP(0, best0, bi0)                                   \
            STEP(1, best1, bi1)                                   \
        }

    // A/B register double-buffer (R12 structure), all-LDS sourcing.
    float4 Aea[4], Aeb[4]; float Ae2[4];
    float4 Bea[4], Beb[4]; float Be2[4];
    LOADG_L(0, Aea, Aeb, Ae2)
    for (int i0 = 0; i0 < NE - 8; i0 += 8) {
        LOADG_L(i0 + 4, Bea, Beb, Be2)
        STEP4(Aea, Aeb, Ae2, i0)
        LOADG_L(i0 + 8, Aea, Aeb, Ae2)
        STEP4(Bea, Beb, Be2, i0 + 4)
    }
    // Tail: i0 = NE-8; A holds group for NE-8.
    LOADG_L(NE - 4, Bea, Beb, Be2)
    STEP4(Aea, Aeb, Ae2, NE - 8)
    STEP4(Bea, Beb, Be2, NE - 4)

    #undef STEP4
    #undef LOADG_L
    #undef STEP

    // Epilogue per position: gather code (global, L1/L2-hot; unchanged
    // validated path), write z_q + idx, loss partial.
    float lacc = 0.0f;
    #define EPI(pp, biv)                                          \
        {                                                         \
            const int n = t0 + pp * TQ;                           \
            const int b = n >> 15;                                \
            const int s = n & (SPAT - 1);                         \
            const float4 wa = cbg[2 * biv];                       \
            const float4 wb = cbg[2 * biv + 1];                   \
            float ev[ED] = {wa.x, wa.y, wa.z, wa.w,               \
                            wb.x, wb.y, wb.z, wb.w};              \
            float* outq = out + b * BATCH_STRIDE + s;             \
            _Pragma("unroll")                                     \
            for (int c = 0; c < ED; ++c) {                        \
                const float diff = ev[c] - zv[pp][c];             \
                lacc = fmaf(diff, diff, lacc);                    \
                outq[c * CH_STRIDE] = ev[c];                      \
            }                                                     \
            out[IDX_OFF + n] = (float)biv;                        \
            used[biv] = 1;                                        \
        }

    EPI(0, bi0)
    EPI(1, bi1)
    #undef EPI

    // Deterministic block-tree reduction of loss partial (graph replay must
    // revalidate bit-identically -> no float atomics)
    __shared__ float red[256];
    red[tid] = lacc;
    __syncthreads();
    #pragma unroll
    for (int off = 128; off > 0; off >>= 1) {
        if (tid < off) red[tid] += red[tid + off];
        __syncthreads();
    }
    if (tid == 0) partials[blockIdx.x] = red[0];
}

__global__ __launch_bounds__(256)
void vq_final(const float* __restrict__ partials, const int* __restrict__ used,
              float* __restrict__ out) {
    __shared__ float sred[256];
    __shared__ int ured[256];
    const int t = threadIdx.x;
    sred[t] = partials[t] + partials[t + 256];   // 512 block partials
    ured[t] = (used[t] ? 1 : 0) + (used[t + 256] ? 1 : 0)
            + (used[t + 512] ? 1 : 0) + (used[t + 768] ? 1 : 0);
    __syncthreads();
    for (int off = 128; off > 0; off >>= 1) {
        if (t < off) { sred[t] += sred[t + off]; ured[t] += ured[t + off]; }
        __syncthreads();
    }
    if (t == 0) {
        const float M = sred[0] * (1.0f / 2097152.0f);  // exact pow2 scale
        out[LOSS_OFF] = 0.25f * M + M;   // beta*mean + mean (forward values equal)
        out[UNIQ_OFF] = (float)ured[0];
    }
}

extern "C" void kernel_launch(void* const* d_in, const int* in_sizes, int n_in,
                              void* d_out, int out_size, void* d_ws, size_t ws_size,
                              hipStream_t stream) {
    const float* z   = (const float*)d_in[0];
    const float* emb = (const float*)d_in[1];
    float* out = (float*)d_out;

    int*   used     = (int*)d_ws;
    float* e2g      = (float*)((char*)d_ws + 4096);
    float* partials = (float*)((char*)d_ws + 8192);

    vq_prep<<<4, 256, 0, stream>>>(emb, used, e2g);
    vq_main<<<NBLK, 256, 0, stream>>>(z, emb, e2g, out, used, partials);
    vq_final<<<1, 256, 0, stream>>>(partials, used, out);
}